// Round 2
// baseline (311.622 us; speedup 1.0000x reference)
//
#include <hip/hip_runtime.h>
#include <math.h>

// Detector loss: N=65536 samples, G=7 (49 cells), A=3 anchors, C=2 classes.
// bbox_ : (N,15,7,7) predictions, channel 5a+0 = objectness(a), 5a+1..5a+4 = x,y,w,h
// bbox  : (N, 5,7,7) GT,          channel 0 = prob map,        1..4       = x,y,w,h
// cls_  : (N,2) logits; cls : (N,) labels in {1,2}
// out   : scalar fp32
//
// R1: one sample per wave (was 8 serial/wave -> latency-chain-bound ~100us);
//     ballot-argmax; epilogue spread over lanes 49-53; two-stage reduction
//     (no atomics, no pre-zero kernel).

static constexpr int GG_ = 49;

__global__ __launch_bounds__(256) void loss_kernel(
    const float* __restrict__ pr_all,     // bbox_
    const float* __restrict__ cls_logits, // cls_
    const float* __restrict__ gt_all,     // bbox
    const int*   __restrict__ cls_lbl,    // cls
    float* __restrict__ partial, int N)
{
    const int lane = threadIdx.x & 63;
    const int n    = blockIdx.x * 4 + (threadIdx.x >> 6);   // one sample per wave
    const float invG   = 1.0f / 7.0f;
    const float invN   = 1.0f / (float)N;
    const float invN49 = invN * (1.0f / 49.0f);

    float acc = 0.0f;

    if (n < N) {
        const float* gt = gt_all + (size_t)n * (5  * GG_);
        const float* pr = pr_all + (size_t)n * (15 * GG_);

        // ---- coalesced loads, all issued up front ----
        float t = -1.0f, p0 = 0.5f, p1 = 0.5f, p2 = 0.5f;
        if (lane < GG_) {
            t  = gt[lane];
            p0 = pr[lane];
            p1 = pr[5  * GG_ + lane];
            p2 = pr[10 * GG_ + lane];
        }
        float x0 = 0.0f, x1 = 0.0f; int cl = 0;
        if (lane == 53) {                       // CE inputs, off the critical chain
            x0 = cls_logits[2 * n];
            x1 = cls_logits[2 * n + 1];
            cl = cls_lbl[n] - 1;
        }

        // ---- all 6 logs precomputed (independent of argmax) ----
        float lp0 = 0, lp1 = 0, lp2 = 0, l1p0 = 0, l1p1 = 0, l1p2 = 0;
        if (lane < GG_) {
            lp0  = __logf(p0);         lp1  = __logf(p1);         lp2  = __logf(p2);
            l1p0 = __logf(1.0f - p0);  l1p1 = __logf(1.0f - p1);  l1p2 = __logf(1.0f - p2);
        }

        // ---- argmax: max-butterfly + ballot (min-index tie-break via ffsll) ----
        float v = t;
        #pragma unroll
        for (int off = 32; off; off >>= 1) v = fmaxf(v, __shfl_xor(v, off));
        unsigned long long msk = __ballot(t == v);   // lanes>=49 have t=-1 < v
        const int m  = __ffsll(msk) - 1;             // wave-uniform
        const int mi = m / 7, mj = m - mi * 7;
        const float jf = (float)mj, if_ = (float)mi;

        // ---- scattered gathers at cell m ----
        float cellv = 0.0f;
        if (lane >= 1 && lane <= 4) {
            cellv = gt[lane * GG_ + m];              // GT x,y,w,h
        } else if (lane >= 5 && lane < 17) {
            int k = lane - 5;
            int a = k >> 2, c = k & 3;
            cellv = pr[(5 * a + 1 + c) * GG_ + m];   // anchor coords
        }

        const float g1 = __shfl(cellv, 1);
        const float g2 = __shfl(cellv, 2);
        const float g3 = __shfl(cellv, 3);
        const float g4 = __shfl(cellv, 4);

        const float tx  = (g1 + jf) * invG;
        const float ty  = (g2 + if_) * invG;
        const float tx1 = tx - g3 * 0.5f, tx2 = tx + g3 * 0.5f;
        const float ty1 = ty - g4 * 0.5f, ty2 = ty + g4 * 0.5f;
        const float tarea = (tx2 - tx1) * (ty2 - ty1);

        // ---- IoU argmax over 3 anchors (strict > => first index on ties) ----
        int best = 0; float bestIoU = -1.0f;
        #pragma unroll
        for (int a = 0; a < 3; a++) {
            float c1 = __shfl(cellv, 5 + 4 * a + 0);
            float c2 = __shfl(cellv, 5 + 4 * a + 1);
            float c3 = __shfl(cellv, 5 + 4 * a + 2);
            float c4 = __shfl(cellv, 5 + 4 * a + 3);
            float ax  = (c1 + jf) * invG;
            float ay  = (c2 + if_) * invG;
            float ax1 = ax - c3 * 0.5f, ax2 = ax + c3 * 0.5f;
            float ay1 = ay - c4 * 0.5f, ay2 = ay + c4 * 0.5f;
            float iw = fminf(ax2, tx2) - fmaxf(ax1, tx1); iw = fmaxf(iw, 0.0f);
            float ih = fminf(ay2, ty2) - fmaxf(ay1, ty1); ih = fmaxf(ih, 0.0f);
            float inter = iw * ih;
            float uni   = (ax2 - ax1) * (ay2 - ay1) + tarea - inter;
            float iou   = inter / (uni + 1e-9f);
            if (iou > bestIoU) { bestIoU = iou; best = a; }
        }

        const float px = __shfl(cellv, 5 + 4 * best + 0);
        const float py = __shfl(cellv, 5 + 4 * best + 1);
        const float pw = __shfl(cellv, 5 + 4 * best + 2);
        const float ph = __shfl(cellv, 5 + 4 * best + 3);

        // ---- prob_loss: sum -log(1-p) over 3 channels; best channel gets
        //      the -t*(log p - log(1-p)) correction (target = full GT map) ----
        if (lane < GG_) {
            float s = -(l1p0 + l1p1 + l1p2);
            float lpb  = (best == 0) ? lp0  : ((best == 1) ? lp1  : lp2);
            float l1pb = (best == 0) ? l1p0 : ((best == 1) ? l1p1 : l1p2);
            s -= t * (lpb - l1pb);
            acc += s * invN49;
        }

        // ---- coord/size/CE spread over idle lanes 49..53 ----
        if (lane == 49) {
            acc += -(g1 * __logf(px) + (1.0f - g1) * __logf(1.0f - px));
        } else if (lane == 50) {
            acc += -(g2 * __logf(py) + (1.0f - g2) * __logf(1.0f - py));
        } else if (lane == 51) {
            acc += fabsf(__logf(pw) - __logf(g3));
        } else if (lane == 52) {
            acc += fabsf(__logf(ph) - __logf(g4));
        } else if (lane == 53) {
            float mx  = fmaxf(x0, x1);
            float lse = mx + __logf(__expf(x0 - mx) + __expf(x1 - mx));
            float lp  = ((cl == 0) ? x0 : x1) - lse;
            acc += -lp * invN;
        }
    }

    // ---- block reduction -> per-block partial (no atomics) ----
    #pragma unroll
    for (int off = 32; off; off >>= 1) acc += __shfl_xor(acc, off);
    __shared__ float wsum[4];
    if (lane == 0) wsum[threadIdx.x >> 6] = acc;
    __syncthreads();
    if (threadIdx.x == 0)
        partial[blockIdx.x] = wsum[0] + wsum[1] + wsum[2] + wsum[3];
}

__global__ __launch_bounds__(256) void reduce_kernel(
    const float* __restrict__ partial, float* __restrict__ out, int M)
{
    const int lane = threadIdx.x & 63;
    float s = 0.0f;
    for (int i = threadIdx.x; i < M; i += 256) s += partial[i];
    #pragma unroll
    for (int off = 32; off; off >>= 1) s += __shfl_xor(s, off);
    __shared__ float wsum[4];
    if (lane == 0) wsum[threadIdx.x >> 6] = s;
    __syncthreads();
    if (threadIdx.x == 0) out[0] = wsum[0] + wsum[1] + wsum[2] + wsum[3];
}

extern "C" void kernel_launch(void* const* d_in, const int* in_sizes, int n_in,
                              void* d_out, int out_size, void* d_ws, size_t ws_size,
                              hipStream_t stream) {
    const float* bbox_p = (const float*)d_in[0];   // (N,15,7,7)
    const float* cls_p  = (const float*)d_in[1];   // (N,2)
    const float* bbox_g = (const float*)d_in[2];   // (N,5,7,7)
    const int*   cls_l  = (const int*)d_in[3];     // (N,)
    float* out = (float*)d_out;
    const int N = in_sizes[3];

    const int nblocks = (N + 3) / 4;               // one wave per sample, 4 waves/block
    float* partial = (float*)d_ws;                 // nblocks floats << ws_size

    hipLaunchKernelGGL(loss_kernel, dim3(nblocks), dim3(256), 0, stream,
                       bbox_p, cls_p, bbox_g, cls_l, partial, N);
    hipLaunchKernelGGL(reduce_kernel, dim3(1), dim3(256), 0, stream,
                       partial, out, nblocks);
}